// Round 26
// baseline (129.787 us; speedup 1.0000x reference)
//
#include <hip/hip_runtime.h>

#define N_LOC 100000
#define N_EVT 100000
#define N_EDGE 1600000
#define NB 391        // buckets of 256 dst values
#define NBIN 391      // bin blocks: ceil(N_EDGE/TILE)
#define SEGCAP 48     // per (block,bucket) segment capacity (mean 10.5)
#define BCAPP 9216    // padded csr capacity per bucket
#define TILE 4096     // edges per bin block (256 thr x 16)
#define RBLK 64       // rows per block in dense kernels (4 waves x 16)
#define DGRID 1563    // ceil(100000/64)

typedef short bf16x8 __attribute__((ext_vector_type(8)));
typedef float f32x4  __attribute__((ext_vector_type(4)));

__device__ __forceinline__ unsigned bf16_rne(float x) {
    unsigned u = __float_as_uint(x);
    return (u + 0x7fffu + ((u >> 16) & 1u)) >> 16;
}
__device__ __forceinline__ float bf_lo(unsigned u) { return __uint_as_float(u << 16); }
__device__ __forceinline__ float bf_hi(unsigned u) { return __uint_as_float(u & 0xffff0000u); }

// Build a bf16x8 fragment from 8 contiguous fp32 (two float4 loads).
__device__ __forceinline__ bf16x8 frag_from_f32(const float* p) {
    float4 v0 = *(const float4*)p;
    float4 v1 = *(const float4*)(p + 4);
    uint4 pk = make_uint4(bf16_rne(v0.x) | (bf16_rne(v0.y) << 16),
                          bf16_rne(v0.z) | (bf16_rne(v0.w) << 16),
                          bf16_rne(v1.x) | (bf16_rne(v1.y) << 16),
                          bf16_rne(v1.z) | (bf16_rne(v1.w) << 16));
    return *(bf16x8*)&pk;
}

// ---------------------------------------------------------------------------
// k_prep (24 blocks): pack Wt_evt/Wt_loc transposed bf16 in global (read by
// all dense blocks from L1/L2); zero the dummy evt row.
// ---------------------------------------------------------------------------
__global__ __launch_bounds__(256) void k_prep(
    const float* __restrict__ W_evt, const float* __restrict__ W_loc,
    unsigned short* __restrict__ Wt_evt,  // [64][128]
    unsigned short* __restrict__ Wt_loc,  // [64][160] (zero tail 144..159)
    unsigned* __restrict__ dummy_row)
{
    const int g0 = blockIdx.x * 256 + threadIdx.x;
    const int gs = gridDim.x * 256;
    for (int idx = g0; idx < 64 * 64; idx += gs) {
        int kp = idx >> 6, c = idx & 63;
        *(unsigned*)&Wt_evt[c * 128 + 2 * kp] =
            bf16_rne(W_evt[(2 * kp + 0) * 64 + c]) |
            (bf16_rne(W_evt[(2 * kp + 1) * 64 + c]) << 16);
    }
    for (int idx = g0; idx < 80 * 64; idx += gs) {
        int kp = idx >> 6, c = idx & 63;
        unsigned v = 0;
        if (kp < 72)
            v = bf16_rne(W_loc[(2 * kp + 0) * 64 + c]) |
                (bf16_rne(W_loc[(2 * kp + 1) * 64 + c]) << 16);
        *(unsigned*)&Wt_loc[c * 160 + 2 * kp] = v;
    }
    if (blockIdx.x == 0 && threadIdx.x < 32) dummy_row[threadIdx.x] = 0u;
}

// ---------------------------------------------------------------------------
// k_front hybrid: bin role = seg/cntm (r25, best backend); dense roles =
// LDS-free (r19: per-lane A from global + reg cvt, B from L2-hot Wt_*).
// LDS = bin role's 1.6 KB only -> dense occupancy not LDS-capped.
// ---------------------------------------------------------------------------
__global__ __launch_bounds__(256) void k_front(
    const float* __restrict__ evt_feat, const unsigned short* __restrict__ Wt_evt,
    const float* __restrict__ b_evt, unsigned short* __restrict__ evtb,
    const float* __restrict__ loc_feat, const int* __restrict__ qid,
    const float* __restrict__ emb, const unsigned short* __restrict__ Wt_loc,
    const float* __restrict__ b_loc, unsigned short* __restrict__ locxb,
    const int* __restrict__ ei, int* __restrict__ cntm,
    unsigned* __restrict__ seg)
{
    __shared__ int h[NB];
    const int bid = blockIdx.x;
    const int t = threadIdx.x;

    if (bid < NBIN) {
        // ---------------- bin role (seg/cntm, r25) ----------------
        for (int i = t; i < NB; i += 256) h[i] = 0;
        __syncthreads();
        const int e0 = bid * TILE;
        int srcv[16], dstv[16], rnk[16];
#pragma unroll
        for (int j = 0; j < 16; ++j) {
            int e = e0 + j * 256 + t;
            if (e < N_EDGE) {
                srcv[j] = ei[e];
                dstv[j] = ei[N_EDGE + e];
                rnk[j] = atomicAdd(&h[dstv[j] >> 8], 1);
            }
        }
        __syncthreads();
        for (int i = t; i < NB; i += 256)
            cntm[(size_t)bid * NB + i] = min(h[i], SEGCAP);
#pragma unroll
        for (int j = 0; j < 16; ++j) {
            int e = e0 + j * 256 + t;
            if (e < N_EDGE && rnk[j] < SEGCAP)
                seg[((size_t)bid * NB + (dstv[j] >> 8)) * SEGCAP + rnk[j]] =
                    (unsigned)srcv[j] | ((unsigned)(dstv[j] & 255) << 24);
        }
        return;
    }

    const int lane = t & 63;
    const int w = t >> 6;
    const int colL = lane & 15;
    const int kq = lane >> 4;

    int db = bid - NBIN;
    if (db < DGRID) {
        // ---------------- evt role (LDS-free, r19) ----------------
        const int gbase = db * RBLK;
        const int arow = min(gbase + 16 * w + colL, N_EVT - 1);
        const float* frow = evt_feat + (size_t)arow * 128;
        f32x4 acc0 = {0.f, 0.f, 0.f, 0.f}, acc1 = acc0, acc2 = acc0, acc3 = acc0;
#pragma unroll
        for (int s = 0; s < 4; ++s) {
            const int kb = s * 32 + kq * 8;
            bf16x8 a  = frag_from_f32(frow + kb);
            bf16x8 b0 = *(const bf16x8*)&Wt_evt[(colL +  0) * 128 + kb];
            bf16x8 b1 = *(const bf16x8*)&Wt_evt[(colL + 16) * 128 + kb];
            bf16x8 b2 = *(const bf16x8*)&Wt_evt[(colL + 32) * 128 + kb];
            bf16x8 b3 = *(const bf16x8*)&Wt_evt[(colL + 48) * 128 + kb];
            acc0 = __builtin_amdgcn_mfma_f32_16x16x32_bf16(a, b0, acc0, 0, 0, 0);
            acc1 = __builtin_amdgcn_mfma_f32_16x16x32_bf16(a, b1, acc1, 0, 0, 0);
            acc2 = __builtin_amdgcn_mfma_f32_16x16x32_bf16(a, b2, acc2, 0, 0, 0);
            acc3 = __builtin_amdgcn_mfma_f32_16x16x32_bf16(a, b3, acc3, 0, 0, 0);
        }
        const float bias0 = b_evt[colL +  0];
        const float bias1 = b_evt[colL + 16];
        const float bias2 = b_evt[colL + 32];
        const float bias3 = b_evt[colL + 48];
        const int rbase = gbase + 16 * w + kq * 4;
#pragma unroll
        for (int j = 0; j < 4; ++j) {
            int grow = rbase + j;
            if (grow < N_EVT) {
                size_t o = (size_t)grow * 64;
                evtb[o + colL +  0] = (unsigned short)bf16_rne(fmaxf(acc0[j] + bias0, 0.f));
                evtb[o + colL + 16] = (unsigned short)bf16_rne(fmaxf(acc1[j] + bias1, 0.f));
                evtb[o + colL + 32] = (unsigned short)bf16_rne(fmaxf(acc2[j] + bias2, 0.f));
                evtb[o + colL + 48] = (unsigned short)bf16_rne(fmaxf(acc3[j] + bias3, 0.f));
            }
        }
        return;
    }

    // ---------------- loc role (LDS-free, r19) ----------------
    {
        db -= DGRID;
        const int gbase = db * RBLK;
        const int arow = min(gbase + 16 * w + colL, N_LOC - 1);
        const float* frow = loc_feat + (size_t)arow * 128;
        f32x4 acc0 = {0.f, 0.f, 0.f, 0.f}, acc1 = acc0, acc2 = acc0, acc3 = acc0;
#pragma unroll
        for (int s = 0; s < 4; ++s) {
            const int kb = s * 32 + kq * 8;
            bf16x8 a  = frag_from_f32(frow + kb);
            bf16x8 b0 = *(const bf16x8*)&Wt_loc[(colL +  0) * 160 + kb];
            bf16x8 b1 = *(const bf16x8*)&Wt_loc[(colL + 16) * 160 + kb];
            bf16x8 b2 = *(const bf16x8*)&Wt_loc[(colL + 32) * 160 + kb];
            bf16x8 b3 = *(const bf16x8*)&Wt_loc[(colL + 48) * 160 + kb];
            acc0 = __builtin_amdgcn_mfma_f32_16x16x32_bf16(a, b0, acc0, 0, 0, 0);
            acc1 = __builtin_amdgcn_mfma_f32_16x16x32_bf16(a, b1, acc1, 0, 0, 0);
            acc2 = __builtin_amdgcn_mfma_f32_16x16x32_bf16(a, b2, acc2, 0, 0, 0);
            acc3 = __builtin_amdgcn_mfma_f32_16x16x32_bf16(a, b3, acc3, 0, 0, 0);
        }
        {   // s = 4: k 128..159 = emb(16) || zeros(16)
            const int kb = 128 + kq * 8;
            bf16x8 a;
            if (kq < 2) {
                int q = qid[arow];
                a = frag_from_f32(emb + (size_t)q * 16 + kq * 8);
            } else {
                uint4 z = make_uint4(0, 0, 0, 0);
                a = *(bf16x8*)&z;
            }
            bf16x8 b0 = *(const bf16x8*)&Wt_loc[(colL +  0) * 160 + kb];
            bf16x8 b1 = *(const bf16x8*)&Wt_loc[(colL + 16) * 160 + kb];
            bf16x8 b2 = *(const bf16x8*)&Wt_loc[(colL + 32) * 160 + kb];
            bf16x8 b3 = *(const bf16x8*)&Wt_loc[(colL + 48) * 160 + kb];
            acc0 = __builtin_amdgcn_mfma_f32_16x16x32_bf16(a, b0, acc0, 0, 0, 0);
            acc1 = __builtin_amdgcn_mfma_f32_16x16x32_bf16(a, b1, acc1, 0, 0, 0);
            acc2 = __builtin_amdgcn_mfma_f32_16x16x32_bf16(a, b2, acc2, 0, 0, 0);
            acc3 = __builtin_amdgcn_mfma_f32_16x16x32_bf16(a, b3, acc3, 0, 0, 0);
        }
        const float bias0 = b_loc[colL +  0];
        const float bias1 = b_loc[colL + 16];
        const float bias2 = b_loc[colL + 32];
        const float bias3 = b_loc[colL + 48];
        const int rbase = gbase + 16 * w + kq * 4;
#pragma unroll
        for (int j = 0; j < 4; ++j) {
            int grow = rbase + j;
            if (grow < N_LOC) {
                size_t o = (size_t)grow * 64;
                locxb[o + colL +  0] = (unsigned short)bf16_rne(fmaxf(acc0[j] + bias0, 0.f));
                locxb[o + colL + 16] = (unsigned short)bf16_rne(fmaxf(acc1[j] + bias1, 0.f));
                locxb[o + colL + 32] = (unsigned short)bf16_rne(fmaxf(acc2[j] + bias2, 0.f));
                locxb[o + colL + 48] = (unsigned short)bf16_rne(fmaxf(acc3[j] + bias3, 0.f));
            }
        }
    }
}

// ---------------------------------------------------------------------------
// k_bfill: one block per bucket. Reads the 391-count column + segments.
// Pass 1: LDS degree histogram. Pad-to-16 scan -> deg/row_ex (fixed stride
// BCAPP). Pass 2: cursor scatter into csr + dummy pad fill. (r25)
// ---------------------------------------------------------------------------
__global__ __launch_bounds__(256) void k_bfill(const int* __restrict__ cntm,
                                               const unsigned* __restrict__ seg,
                                               int* __restrict__ deg,
                                               int* __restrict__ row_ex,
                                               int* __restrict__ csr) {
    __shared__ int cnt0[NBIN];
    __shared__ int degl[256];
    __shared__ int sc[256];
    __shared__ int cur[256];
    const int b = blockIdx.x;
    const int t = threadIdx.x;
    for (int i = t; i < NBIN; i += 256) cnt0[i] = cntm[(size_t)i * NB + b];
    degl[t] = 0;
    __syncthreads();
    for (int blk = t; blk < NBIN; blk += 256) {
        const int c = cnt0[blk];
        const unsigned* s = seg + ((size_t)blk * NB + b) * SEGCAP;
        for (int j = 0; j < c; ++j) atomicAdd(&degl[s[j] >> 24], 1);
    }
    __syncthreads();
    const int v = degl[t];
    const int vpad = (v + 15) & ~15;
    sc[t] = vpad;
    __syncthreads();
    for (int off = 1; off < 256; off <<= 1) {
        int x = (t >= off) ? sc[t - off] : 0;
        __syncthreads();
        sc[t] += x;
        __syncthreads();
    }
    const int ex = b * BCAPP + sc[t] - vpad;
    const int loc = b * 256 + t;
    if (loc < N_LOC) { deg[loc] = v; row_ex[loc] = ex; }
    cur[t] = ex;
    __syncthreads();
    for (int blk = t; blk < NBIN; blk += 256) {
        const int c = cnt0[blk];
        const unsigned* s = seg + ((size_t)blk * NB + b) * SEGCAP;
        for (int j = 0; j < c; ++j) {
            unsigned u = s[j];
            int pos = atomicAdd(&cur[u >> 24], 1);
            csr[pos] = (int)(u & 0x00FFFFFFu);
        }
    }
    for (int j = v; j < vpad; ++j) csr[ex + j] = N_EVT;
}

// ---------------------------------------------------------------------------
// K4: mean[loc] from bf16-packed evt rows -> bf16-packed mean. (r14)
// ---------------------------------------------------------------------------
__global__ __launch_bounds__(256, 8) void k_aggr(const unsigned* __restrict__ evtb,
                                                 const int* __restrict__ row_ex,
                                                 const int* __restrict__ deg,
                                                 const int* __restrict__ csr,
                                                 unsigned* __restrict__ meanb, int n) {
    const int lane = threadIdx.x & 63;
    int wid = (blockIdx.x * 256 + threadIdx.x) >> 6;
    wid = __builtin_amdgcn_readfirstlane(wid);
    if (wid >= n) return;
    const int beg = row_ex[wid];
    const int cnt = deg[wid];
    const int cntp = (cnt + 15) & ~15;
    const int half = lane >> 5;
    const int c = lane & 31;
    float a0 = 0.0f, a1 = 0.0f;
    for (int i = 0; i < cntp; i += 16) {
        const int bb = beg + i + half;
        int s0 = csr[bb +  0];
        int s1 = csr[bb +  2];
        int s2 = csr[bb +  4];
        int s3 = csr[bb +  6];
        int s4 = csr[bb +  8];
        int s5 = csr[bb + 10];
        int s6 = csr[bb + 12];
        int s7 = csr[bb + 14];
        unsigned u0 = evtb[(size_t)s0 * 32 + c];
        unsigned u1 = evtb[(size_t)s1 * 32 + c];
        unsigned u2 = evtb[(size_t)s2 * 32 + c];
        unsigned u3 = evtb[(size_t)s3 * 32 + c];
        unsigned u4 = evtb[(size_t)s4 * 32 + c];
        unsigned u5 = evtb[(size_t)s5 * 32 + c];
        unsigned u6 = evtb[(size_t)s6 * 32 + c];
        unsigned u7 = evtb[(size_t)s7 * 32 + c];
        a0 += ((bf_lo(u0) + bf_lo(u1)) + (bf_lo(u2) + bf_lo(u3))) +
              ((bf_lo(u4) + bf_lo(u5)) + (bf_lo(u6) + bf_lo(u7)));
        a1 += ((bf_hi(u0) + bf_hi(u1)) + (bf_hi(u2) + bf_hi(u3))) +
              ((bf_hi(u4) + bf_hi(u5)) + (bf_hi(u6) + bf_hi(u7)));
    }
    a0 += __shfl_xor(a0, 32);
    a1 += __shfl_xor(a1, 32);
    const float inv = 1.0f / (float)max(cnt, 1);
    if (lane < 32)
        meanb[(size_t)wid * 32 + c] = bf16_rne(a0 * inv) | (bf16_rne(a1 * inv) << 16);
}

// ---------------------------------------------------------------------------
// K5 (MFMA): x2 = relu([mean||locx] @ [W_l;W_r] + b_l);
//            h = relu(x2 @ W_h1 + b_h1); out = h @ W_h2 + b_h2. (r25)
// ---------------------------------------------------------------------------
__global__ __launch_bounds__(256) void k_comb(
    const unsigned* __restrict__ meanb, const unsigned* __restrict__ locxb,
    const float* __restrict__ W_l, const float* __restrict__ b_l,
    const float* __restrict__ W_r,
    const float* __restrict__ W_h1, const float* __restrict__ b_h1,
    const float* __restrict__ W_h2, const float* __restrict__ b_h2,
    float* __restrict__ out, int n)
{
    __shared__ unsigned short sA[64 * 136];
    __shared__ unsigned short sBc[64 * 136];
    __shared__ unsigned short sX[64 * 72];
    __shared__ unsigned short sBh[32 * 72];
    const int t = threadIdx.x;
    const int gbase = blockIdx.x * RBLK;
    for (int idx = t; idx < 64 * 64; idx += 256) {
        int kp = idx >> 6, c = idx & 63;
        float w0, w1;
        if (kp < 32) { w0 = W_l[(2 * kp + 0) * 64 + c]; w1 = W_l[(2 * kp + 1) * 64 + c]; }
        else { w0 = W_r[(2 * kp - 64 + 0) * 64 + c]; w1 = W_r[(2 * kp - 64 + 1) * 64 + c]; }
        *(unsigned*)&sBc[c * 136 + 2 * kp] = bf16_rne(w0) | (bf16_rne(w1) << 16);
    }
    for (int idx = t; idx < 32 * 32; idx += 256) {
        int kp = idx >> 5, c = idx & 31;
        float w0 = W_h1[(2 * kp + 0) * 32 + c];
        float w1 = W_h1[(2 * kp + 1) * 32 + c];
        *(unsigned*)&sBh[c * 72 + 2 * kp] = bf16_rne(w0) | (bf16_rne(w1) << 16);
    }
    for (int idx = t; idx < RBLK * 32; idx += 256) {
        int row = idx >> 5, q = idx & 31;
        int grow = gbase + row;
        uint2 p = make_uint2(0, 0);
        if (grow < n) {
            p = (q < 16) ? ((const uint2*)meanb)[(size_t)grow * 16 + q]
                         : ((const uint2*)locxb)[(size_t)grow * 16 + (q - 16)];
        }
        *(uint2*)&sA[row * 136 + q * 4] = p;
    }
    __syncthreads();
    const int lane = t & 63;
    const int w = t >> 6;
    const int colL = lane & 15;
    const int kq = lane >> 4;
    f32x4 acc0 = {0.f, 0.f, 0.f, 0.f}, acc1 = acc0, acc2 = acc0, acc3 = acc0;
#pragma unroll
    for (int s = 0; s < 4; ++s) {
        const int kb = s * 32 + kq * 8;
        bf16x8 a  = *(const bf16x8*)&sA[(16 * w + colL) * 136 + kb];
        bf16x8 b0 = *(const bf16x8*)&sBc[(colL +  0) * 136 + kb];
        bf16x8 b1 = *(const bf16x8*)&sBc[(colL + 16) * 136 + kb];
        bf16x8 b2 = *(const bf16x8*)&sBc[(colL + 32) * 136 + kb];
        bf16x8 b3 = *(const bf16x8*)&sBc[(colL + 48) * 136 + kb];
        acc0 = __builtin_amdgcn_mfma_f32_16x16x32_bf16(a, b0, acc0, 0, 0, 0);
        acc1 = __builtin_amdgcn_mfma_f32_16x16x32_bf16(a, b1, acc1, 0, 0, 0);
        acc2 = __builtin_amdgcn_mfma_f32_16x16x32_bf16(a, b2, acc2, 0, 0, 0);
        acc3 = __builtin_amdgcn_mfma_f32_16x16x32_bf16(a, b3, acc3, 0, 0, 0);
    }
    {
        const float bias0 = b_l[colL +  0];
        const float bias1 = b_l[colL + 16];
        const float bias2 = b_l[colL + 32];
        const float bias3 = b_l[colL + 48];
#pragma unroll
        for (int j = 0; j < 4; ++j) {
            int row = 16 * w + kq * 4 + j;
            sX[row * 72 + colL +  0] = (unsigned short)bf16_rne(fmaxf(acc0[j] + bias0, 0.f));
            sX[row * 72 + colL + 16] = (unsigned short)bf16_rne(fmaxf(acc1[j] + bias1, 0.f));
            sX[row * 72 + colL + 32] = (unsigned short)bf16_rne(fmaxf(acc2[j] + bias2, 0.f));
            sX[row * 72 + colL + 48] = (unsigned short)bf16_rne(fmaxf(acc3[j] + bias3, 0.f));
        }
    }
    // wave w wrote rows 16w..16w+15 and reads only those: no barrier needed.
    f32x4 h0 = {0.f, 0.f, 0.f, 0.f}, h1 = h0;
#pragma unroll
    for (int s = 0; s < 2; ++s) {
        const int kb = s * 32 + kq * 8;
        bf16x8 a  = *(const bf16x8*)&sX[(16 * w + colL) * 72 + kb];
        bf16x8 b0 = *(const bf16x8*)&sBh[(colL +  0) * 72 + kb];
        bf16x8 b1 = *(const bf16x8*)&sBh[(colL + 16) * 72 + kb];
        h0 = __builtin_amdgcn_mfma_f32_16x16x32_bf16(a, b0, h0, 0, 0, 0);
        h1 = __builtin_amdgcn_mfma_f32_16x16x32_bf16(a, b1, h1, 0, 0, 0);
    }
    {
        const float bh1c0 = b_h1[colL];
        const float bh1c1 = b_h1[colL + 16];
        const float wh2c0 = W_h2[colL];
        const float wh2c1 = W_h2[colL + 16];
        const float bh2 = b_h2[0];
#pragma unroll
        for (int j = 0; j < 4; ++j) {
            float p = fmaxf(h0[j] + bh1c0, 0.f) * wh2c0 +
                      fmaxf(h1[j] + bh1c1, 0.f) * wh2c1;
            p += __shfl_xor(p, 1);
            p += __shfl_xor(p, 2);
            p += __shfl_xor(p, 4);
            p += __shfl_xor(p, 8);
            int grow = gbase + 16 * w + kq * 4 + j;
            if (colL == 0 && grow < n) out[grow] = p + bh2;
        }
    }
}

// ---------------------------------------------------------------------------
extern "C" void kernel_launch(void* const* d_in, const int* in_sizes, int n_in,
                              void* d_out, int out_size, void* d_ws, size_t ws_size,
                              hipStream_t stream) {
    const float* loc_feat = (const float*)d_in[0];
    const float* evt_feat = (const float*)d_in[1];
    const int*   qid      = (const int*)d_in[2];
    const int*   ei       = (const int*)d_in[3];
    const float* emb      = (const float*)d_in[4];
    const float* W_loc    = (const float*)d_in[5];
    const float* b_loc    = (const float*)d_in[6];
    const float* W_evt    = (const float*)d_in[7];
    const float* b_evt    = (const float*)d_in[8];
    const float* W_l      = (const float*)d_in[9];
    const float* b_l      = (const float*)d_in[10];
    const float* W_r      = (const float*)d_in[11];
    const float* W_h1     = (const float*)d_in[12];
    const float* b_h1     = (const float*)d_in[13];
    const float* W_h2     = (const float*)d_in[14];
    const float* b_h2     = (const float*)d_in[15];
    float* out = (float*)d_out;

    char* ws = (char*)d_ws;
    size_t off = 0;
    auto alloc = [&](size_t bytes) -> void* {
        void* p = ws + off;
        off += (bytes + 255) & ~(size_t)255;
        return p;
    };
    unsigned* evtb  = (unsigned*)alloc((size_t)(N_EVT + 1) * 32 * 4); // bf16 evt_x + zero row
    unsigned* locxb = (unsigned*)alloc((size_t)N_LOC * 32 * 4);       // 12.8 MB
    unsigned* meanb = (unsigned*)alloc((size_t)N_LOC * 32 * 4);       // 12.8 MB
    unsigned* seg   = (unsigned*)alloc((size_t)NBIN * NB * SEGCAP * 4); // 29.4 MB
    int*   cntm     = (int*)alloc((size_t)NBIN * NB * 4);             // 0.6 MB
    int*   deg      = (int*)alloc((size_t)N_LOC * 4);
    int*   row_ex   = (int*)alloc((size_t)(N_LOC + 1) * 4);
    int*   csr      = (int*)alloc((size_t)NB * BCAPP * 4);            // 14.4 MB
    unsigned short* Wt_evt = (unsigned short*)alloc(64 * 128 * 2);
    unsigned short* Wt_loc = (unsigned short*)alloc(64 * 160 * 2);
    (void)ws_size; (void)in_sizes; (void)n_in; (void)out_size;

    k_prep<<<24, 256, 0, stream>>>(W_evt, W_loc, Wt_evt, Wt_loc,
                                   evtb + (size_t)N_EVT * 32);
    k_front<<<NBIN + 2 * DGRID, 256, 0, stream>>>(
        evt_feat, Wt_evt, b_evt, (unsigned short*)evtb,
        loc_feat, qid, emb, Wt_loc, b_loc, (unsigned short*)locxb,
        ei, cntm, seg);
    k_bfill<<<NB, 256, 0, stream>>>(cntm, seg, deg, row_ex, csr);
    k_aggr<<<N_LOC / 4, 256, 0, stream>>>(evtb, row_ex, deg, csr, meanb, N_LOC);
    k_comb<<<DGRID, 256, 0, stream>>>(meanb, locxb, W_l, b_l, W_r,
                                      W_h1, b_h1, W_h2, b_h2, out, N_LOC);
}

// Round 27
// 124.055 us; speedup vs baseline: 1.0462x; 1.0462x over previous
//
#include <hip/hip_runtime.h>

#define N_LOC 100000
#define N_EVT 100000
#define N_EDGE 1600000
#define NB 391        // buckets of 256 dst values
#define NBIN 391      // bin blocks: ceil(N_EDGE/TILE)
#define SEGCAP 48     // per (block,bucket) segment capacity (mean 10.5)
#define BCAPP 9216    // padded csr capacity per bucket
#define TILE 4096     // edges per bin block (256 thr x 16)
#define RBLK 64       // rows per block in dense kernels (4 waves x 16)
#define DGRID 1563    // ceil(100000/64)

typedef short bf16x8 __attribute__((ext_vector_type(8)));
typedef float f32x4  __attribute__((ext_vector_type(4)));

__device__ __forceinline__ unsigned bf16_rne(float x) {
    unsigned u = __float_as_uint(x);
    return (u + 0x7fffu + ((u >> 16) & 1u)) >> 16;
}
__device__ __forceinline__ float bf_lo(unsigned u) { return __uint_as_float(u << 16); }
__device__ __forceinline__ float bf_hi(unsigned u) { return __uint_as_float(u & 0xffff0000u); }

// ---------------------------------------------------------------------------
// k_front: fused {bin | evt | loc} roles by blockIdx range.
//   bin (blocks 0..390): LDS hist -> unconditional counts matrix + segments
//       (no global atomics, no init dependency). Block 0 zeroes dummy row.
//   evt (next 1563): MFMA evt_x -> bf16 (validated round 11 structure)
//   loc (next 1563): MFMA loc_x -> bf16 (validated round 12 structure)
// ---------------------------------------------------------------------------
__global__ __launch_bounds__(256) void k_front(
    const float* __restrict__ evt_feat, const float* __restrict__ W_evt,
    const float* __restrict__ b_evt, unsigned short* __restrict__ evtb,
    const float* __restrict__ loc_feat, const int* __restrict__ qid,
    const float* __restrict__ emb, const float* __restrict__ W_loc,
    const float* __restrict__ b_loc, unsigned short* __restrict__ locxb,
    const int* __restrict__ ei, int* __restrict__ cntm,
    unsigned* __restrict__ seg, unsigned* __restrict__ dummy_row)
{
    __shared__ __align__(16) unsigned char smem[43008];
    const int bid = blockIdx.x;
    const int t = threadIdx.x;

    if (bid < NBIN) {
        // ---------------- bin role ----------------
        int* h = (int*)smem;  // NB ints
        if (bid == 0 && t < 32) dummy_row[t] = 0u;
        for (int i = t; i < NB; i += 256) h[i] = 0;
        __syncthreads();
        const int e0 = bid * TILE;
        int srcv[16], dstv[16], rnk[16];
#pragma unroll
        for (int j = 0; j < 16; ++j) {
            int e = e0 + j * 256 + t;
            if (e < N_EDGE) {
                srcv[j] = ei[e];
                dstv[j] = ei[N_EDGE + e];
                rnk[j] = atomicAdd(&h[dstv[j] >> 8], 1);
            }
        }
        __syncthreads();
        for (int i = t; i < NB; i += 256)
            cntm[(size_t)bid * NB + i] = min(h[i], SEGCAP);
#pragma unroll
        for (int j = 0; j < 16; ++j) {
            int e = e0 + j * 256 + t;
            if (e < N_EDGE && rnk[j] < SEGCAP)
                seg[((size_t)bid * NB + (dstv[j] >> 8)) * SEGCAP + rnk[j]] =
                    (unsigned)srcv[j] | ((unsigned)(dstv[j] & 255) << 24);
        }
        return;
    }

    const int lane = t & 63;
    const int w = t >> 6;
    const int colL = lane & 15;
    const int kq = lane >> 4;

    int db = bid - NBIN;
    if (db < DGRID) {
        // ---------------- evt role ----------------
        unsigned short* sA = (unsigned short*)smem;          // 64*136
        unsigned short* sB = sA + 64 * 136;                  // 64*136
        const int gbase = db * RBLK;
        for (int idx = t; idx < 4096; idx += 256) {
            int kp = idx >> 6, c = idx & 63;
            float w0 = W_evt[(2 * kp + 0) * 64 + c];
            float w1 = W_evt[(2 * kp + 1) * 64 + c];
            *(unsigned*)&sB[c * 136 + 2 * kp] = bf16_rne(w0) | (bf16_rne(w1) << 16);
        }
        for (int idx = t; idx < RBLK * 32; idx += 256) {
            int row = idx >> 5, c4 = idx & 31;
            int grow = gbase + row;
            float4 v = (grow < N_EVT) ? ((const float4*)evt_feat)[(size_t)grow * 32 + c4]
                                      : make_float4(0.f, 0.f, 0.f, 0.f);
            uint2 p = make_uint2(bf16_rne(v.x) | (bf16_rne(v.y) << 16),
                                 bf16_rne(v.z) | (bf16_rne(v.w) << 16));
            *(uint2*)&sA[row * 136 + c4 * 4] = p;
        }
        __syncthreads();
        f32x4 acc0 = {0.f, 0.f, 0.f, 0.f}, acc1 = acc0, acc2 = acc0, acc3 = acc0;
#pragma unroll
        for (int s = 0; s < 4; ++s) {
            const int kb = s * 32 + kq * 8;
            bf16x8 a  = *(const bf16x8*)&sA[(16 * w + colL) * 136 + kb];
            bf16x8 b0 = *(const bf16x8*)&sB[(colL +  0) * 136 + kb];
            bf16x8 b1 = *(const bf16x8*)&sB[(colL + 16) * 136 + kb];
            bf16x8 b2 = *(const bf16x8*)&sB[(colL + 32) * 136 + kb];
            bf16x8 b3 = *(const bf16x8*)&sB[(colL + 48) * 136 + kb];
            acc0 = __builtin_amdgcn_mfma_f32_16x16x32_bf16(a, b0, acc0, 0, 0, 0);
            acc1 = __builtin_amdgcn_mfma_f32_16x16x32_bf16(a, b1, acc1, 0, 0, 0);
            acc2 = __builtin_amdgcn_mfma_f32_16x16x32_bf16(a, b2, acc2, 0, 0, 0);
            acc3 = __builtin_amdgcn_mfma_f32_16x16x32_bf16(a, b3, acc3, 0, 0, 0);
        }
        const float bias0 = b_evt[colL +  0];
        const float bias1 = b_evt[colL + 16];
        const float bias2 = b_evt[colL + 32];
        const float bias3 = b_evt[colL + 48];
        const int rbase = gbase + 16 * w + kq * 4;
#pragma unroll
        for (int j = 0; j < 4; ++j) {
            int grow = rbase + j;
            if (grow < N_EVT) {
                size_t o = (size_t)grow * 64;
                evtb[o + colL +  0] = (unsigned short)bf16_rne(fmaxf(acc0[j] + bias0, 0.f));
                evtb[o + colL + 16] = (unsigned short)bf16_rne(fmaxf(acc1[j] + bias1, 0.f));
                evtb[o + colL + 32] = (unsigned short)bf16_rne(fmaxf(acc2[j] + bias2, 0.f));
                evtb[o + colL + 48] = (unsigned short)bf16_rne(fmaxf(acc3[j] + bias3, 0.f));
            }
        }
        return;
    }

    // ---------------- loc role ----------------
    {
        db -= DGRID;
        unsigned short* sA = (unsigned short*)smem;          // 64*168
        unsigned short* sB = sA + 64 * 168;                  // 64*168
        const int gbase = db * RBLK;
        for (int idx = t; idx < 72 * 64; idx += 256) {
            int kp = idx >> 6, c = idx & 63;
            float w0 = W_loc[(2 * kp + 0) * 64 + c];
            float w1 = W_loc[(2 * kp + 1) * 64 + c];
            *(unsigned*)&sB[c * 168 + 2 * kp] = bf16_rne(w0) | (bf16_rne(w1) << 16);
        }
        for (int idx = t; idx < 64 * 2; idx += 256) {
            int c = idx >> 1, h2 = idx & 1;
            *(uint4*)&sB[c * 168 + 144 + h2 * 8] = make_uint4(0, 0, 0, 0);
        }
        for (int idx = t; idx < RBLK * 32; idx += 256) {
            int row = idx >> 5, c4 = idx & 31;
            int grow = gbase + row;
            float4 v = (grow < N_LOC) ? ((const float4*)loc_feat)[(size_t)grow * 32 + c4]
                                      : make_float4(0.f, 0.f, 0.f, 0.f);
            uint2 p = make_uint2(bf16_rne(v.x) | (bf16_rne(v.y) << 16),
                                 bf16_rne(v.z) | (bf16_rne(v.w) << 16));
            *(uint2*)&sA[row * 168 + c4 * 4] = p;
        }
        for (int idx = t; idx < RBLK * 4; idx += 256) {
            int row = idx >> 2, e4 = idx & 3;
            int grow = gbase + row;
            int q = (grow < N_LOC) ? qid[grow] : 0;
            float4 v = ((const float4*)emb)[(size_t)q * 4 + e4];
            uint2 p = make_uint2(bf16_rne(v.x) | (bf16_rne(v.y) << 16),
                                 bf16_rne(v.z) | (bf16_rne(v.w) << 16));
            *(uint2*)&sA[row * 168 + 128 + e4 * 4] = p;
        }
        for (int idx = t; idx < RBLK * 2; idx += 256) {
            int row = idx >> 1, h2 = idx & 1;
            *(uint4*)&sA[row * 168 + 144 + h2 * 8] = make_uint4(0, 0, 0, 0);
        }
        __syncthreads();
        f32x4 acc0 = {0.f, 0.f, 0.f, 0.f}, acc1 = acc0, acc2 = acc0, acc3 = acc0;
#pragma unroll
        for (int s = 0; s < 5; ++s) {
            const int kb = s * 32 + kq * 8;
            bf16x8 a  = *(const bf16x8*)&sA[(16 * w + colL) * 168 + kb];
            bf16x8 b0 = *(const bf16x8*)&sB[(colL +  0) * 168 + kb];
            bf16x8 b1 = *(const bf16x8*)&sB[(colL + 16) * 168 + kb];
            bf16x8 b2 = *(const bf16x8*)&sB[(colL + 32) * 168 + kb];
            bf16x8 b3 = *(const bf16x8*)&sB[(colL + 48) * 168 + kb];
            acc0 = __builtin_amdgcn_mfma_f32_16x16x32_bf16(a, b0, acc0, 0, 0, 0);
            acc1 = __builtin_amdgcn_mfma_f32_16x16x32_bf16(a, b1, acc1, 0, 0, 0);
            acc2 = __builtin_amdgcn_mfma_f32_16x16x32_bf16(a, b2, acc2, 0, 0, 0);
            acc3 = __builtin_amdgcn_mfma_f32_16x16x32_bf16(a, b3, acc3, 0, 0, 0);
        }
        const float bias0 = b_loc[colL +  0];
        const float bias1 = b_loc[colL + 16];
        const float bias2 = b_loc[colL + 32];
        const float bias3 = b_loc[colL + 48];
        const int rbase = gbase + 16 * w + kq * 4;
#pragma unroll
        for (int j = 0; j < 4; ++j) {
            int grow = rbase + j;
            if (grow < N_LOC) {
                size_t o = (size_t)grow * 64;
                locxb[o + colL +  0] = (unsigned short)bf16_rne(fmaxf(acc0[j] + bias0, 0.f));
                locxb[o + colL + 16] = (unsigned short)bf16_rne(fmaxf(acc1[j] + bias1, 0.f));
                locxb[o + colL + 32] = (unsigned short)bf16_rne(fmaxf(acc2[j] + bias2, 0.f));
                locxb[o + colL + 48] = (unsigned short)bf16_rne(fmaxf(acc3[j] + bias3, 0.f));
            }
        }
    }
}

// ---------------------------------------------------------------------------
// k_bfill: one block per bucket. Reads the 391-count column + segments.
// Pass 1: LDS degree histogram. Pad-to-16 scan -> deg/row_ex (fixed stride
// BCAPP). Pass 2: cursor scatter into csr + dummy pad fill.
// ---------------------------------------------------------------------------
__global__ __launch_bounds__(256) void k_bfill(const int* __restrict__ cntm,
                                               const unsigned* __restrict__ seg,
                                               int* __restrict__ deg,
                                               int* __restrict__ row_ex,
                                               int* __restrict__ csr) {
    __shared__ int cnt0[NBIN];
    __shared__ int degl[256];
    __shared__ int sc[256];
    __shared__ int cur[256];
    const int b = blockIdx.x;
    const int t = threadIdx.x;
    for (int i = t; i < NBIN; i += 256) cnt0[i] = cntm[(size_t)i * NB + b];
    degl[t] = 0;
    __syncthreads();
    // pass 1: degree histogram
    for (int blk = t; blk < NBIN; blk += 256) {
        const int c = cnt0[blk];
        const unsigned* s = seg + ((size_t)blk * NB + b) * SEGCAP;
        for (int j = 0; j < c; ++j) atomicAdd(&degl[s[j] >> 24], 1);
    }
    __syncthreads();
    const int v = degl[t];
    const int vpad = (v + 15) & ~15;
    sc[t] = vpad;
    __syncthreads();
    for (int off = 1; off < 256; off <<= 1) {
        int x = (t >= off) ? sc[t - off] : 0;
        __syncthreads();
        sc[t] += x;
        __syncthreads();
    }
    const int ex = b * BCAPP + sc[t] - vpad;
    const int loc = b * 256 + t;
    if (loc < N_LOC) { deg[loc] = v; row_ex[loc] = ex; }
    cur[t] = ex;
    __syncthreads();
    // pass 2: scatter
    for (int blk = t; blk < NBIN; blk += 256) {
        const int c = cnt0[blk];
        const unsigned* s = seg + ((size_t)blk * NB + b) * SEGCAP;
        for (int j = 0; j < c; ++j) {
            unsigned u = s[j];
            int pos = atomicAdd(&cur[u >> 24], 1);
            csr[pos] = (int)(u & 0x00FFFFFFu);
        }
    }
    for (int j = v; j < vpad; ++j) csr[ex + j] = N_EVT;
}

// ---------------------------------------------------------------------------
// K4: mean[loc] from bf16-packed evt rows -> bf16-packed mean.
// (validated round 14: padded CSR, tail-free 16-deep gather pipeline)
// ---------------------------------------------------------------------------
__global__ __launch_bounds__(256, 8) void k_aggr(const unsigned* __restrict__ evtb,
                                                 const int* __restrict__ row_ex,
                                                 const int* __restrict__ deg,
                                                 const int* __restrict__ csr,
                                                 unsigned* __restrict__ meanb, int n) {
    const int lane = threadIdx.x & 63;
    int wid = (blockIdx.x * 256 + threadIdx.x) >> 6;
    wid = __builtin_amdgcn_readfirstlane(wid);
    if (wid >= n) return;
    const int beg = row_ex[wid];
    const int cnt = deg[wid];
    const int cntp = (cnt + 15) & ~15;
    const int half = lane >> 5;
    const int c = lane & 31;
    float a0 = 0.0f, a1 = 0.0f;
    for (int i = 0; i < cntp; i += 16) {
        const int bb = beg + i + half;
        int s0 = csr[bb +  0];
        int s1 = csr[bb +  2];
        int s2 = csr[bb +  4];
        int s3 = csr[bb +  6];
        int s4 = csr[bb +  8];
        int s5 = csr[bb + 10];
        int s6 = csr[bb + 12];
        int s7 = csr[bb + 14];
        unsigned u0 = evtb[(size_t)s0 * 32 + c];
        unsigned u1 = evtb[(size_t)s1 * 32 + c];
        unsigned u2 = evtb[(size_t)s2 * 32 + c];
        unsigned u3 = evtb[(size_t)s3 * 32 + c];
        unsigned u4 = evtb[(size_t)s4 * 32 + c];
        unsigned u5 = evtb[(size_t)s5 * 32 + c];
        unsigned u6 = evtb[(size_t)s6 * 32 + c];
        unsigned u7 = evtb[(size_t)s7 * 32 + c];
        a0 += ((bf_lo(u0) + bf_lo(u1)) + (bf_lo(u2) + bf_lo(u3))) +
              ((bf_lo(u4) + bf_lo(u5)) + (bf_lo(u6) + bf_lo(u7)));
        a1 += ((bf_hi(u0) + bf_hi(u1)) + (bf_hi(u2) + bf_hi(u3))) +
              ((bf_hi(u4) + bf_hi(u5)) + (bf_hi(u6) + bf_hi(u7)));
    }
    a0 += __shfl_xor(a0, 32);
    a1 += __shfl_xor(a1, 32);
    const float inv = 1.0f / (float)max(cnt, 1);
    if (lane < 32)
        meanb[(size_t)wid * 32 + c] = bf16_rne(a0 * inv) | (bf16_rne(a1 * inv) << 16);
}

// ---------------------------------------------------------------------------
// K5 (MFMA): x2 = relu([mean||locx] @ [W_l;W_r] + b_l);
//            h = relu(x2 @ W_h1 + b_h1); out = h @ W_h2 + b_h2.
// (validated round 12)
// ---------------------------------------------------------------------------
__global__ __launch_bounds__(256) void k_comb(
    const unsigned* __restrict__ meanb, const unsigned* __restrict__ locxb,
    const float* __restrict__ W_l, const float* __restrict__ b_l,
    const float* __restrict__ W_r,
    const float* __restrict__ W_h1, const float* __restrict__ b_h1,
    const float* __restrict__ W_h2, const float* __restrict__ b_h2,
    float* __restrict__ out, int n)
{
    __shared__ unsigned short sA[64 * 136];
    __shared__ unsigned short sBc[64 * 136];
    __shared__ unsigned short sX[64 * 72];
    __shared__ unsigned short sBh[32 * 72];
    const int t = threadIdx.x;
    const int gbase = blockIdx.x * RBLK;
    for (int idx = t; idx < 64 * 64; idx += 256) {
        int kp = idx >> 6, c = idx & 63;
        float w0, w1;
        if (kp < 32) { w0 = W_l[(2 * kp + 0) * 64 + c]; w1 = W_l[(2 * kp + 1) * 64 + c]; }
        else { w0 = W_r[(2 * kp - 64 + 0) * 64 + c]; w1 = W_r[(2 * kp - 64 + 1) * 64 + c]; }
        *(unsigned*)&sBc[c * 136 + 2 * kp] = bf16_rne(w0) | (bf16_rne(w1) << 16);
    }
    for (int idx = t; idx < 32 * 32; idx += 256) {
        int kp = idx >> 5, c = idx & 31;
        float w0 = W_h1[(2 * kp + 0) * 32 + c];
        float w1 = W_h1[(2 * kp + 1) * 32 + c];
        *(unsigned*)&sBh[c * 72 + 2 * kp] = bf16_rne(w0) | (bf16_rne(w1) << 16);
    }
    for (int idx = t; idx < RBLK * 32; idx += 256) {
        int row = idx >> 5, q = idx & 31;
        int grow = gbase + row;
        uint2 p = make_uint2(0, 0);
        if (grow < n) {
            p = (q < 16) ? ((const uint2*)meanb)[(size_t)grow * 16 + q]
                         : ((const uint2*)locxb)[(size_t)grow * 16 + (q - 16)];
        }
        *(uint2*)&sA[row * 136 + q * 4] = p;
    }
    __syncthreads();
    const int lane = t & 63;
    const int w = t >> 6;
    const int colL = lane & 15;
    const int kq = lane >> 4;
    f32x4 acc0 = {0.f, 0.f, 0.f, 0.f}, acc1 = acc0, acc2 = acc0, acc3 = acc0;
#pragma unroll
    for (int s = 0; s < 4; ++s) {
        const int kb = s * 32 + kq * 8;
        bf16x8 a  = *(const bf16x8*)&sA[(16 * w + colL) * 136 + kb];
        bf16x8 b0 = *(const bf16x8*)&sBc[(colL +  0) * 136 + kb];
        bf16x8 b1 = *(const bf16x8*)&sBc[(colL + 16) * 136 + kb];
        bf16x8 b2 = *(const bf16x8*)&sBc[(colL + 32) * 136 + kb];
        bf16x8 b3 = *(const bf16x8*)&sBc[(colL + 48) * 136 + kb];
        acc0 = __builtin_amdgcn_mfma_f32_16x16x32_bf16(a, b0, acc0, 0, 0, 0);
        acc1 = __builtin_amdgcn_mfma_f32_16x16x32_bf16(a, b1, acc1, 0, 0, 0);
        acc2 = __builtin_amdgcn_mfma_f32_16x16x32_bf16(a, b2, acc2, 0, 0, 0);
        acc3 = __builtin_amdgcn_mfma_f32_16x16x32_bf16(a, b3, acc3, 0, 0, 0);
    }
    {
        const float bias0 = b_l[colL +  0];
        const float bias1 = b_l[colL + 16];
        const float bias2 = b_l[colL + 32];
        const float bias3 = b_l[colL + 48];
#pragma unroll
        for (int j = 0; j < 4; ++j) {
            int row = 16 * w + kq * 4 + j;
            sX[row * 72 + colL +  0] = (unsigned short)bf16_rne(fmaxf(acc0[j] + bias0, 0.f));
            sX[row * 72 + colL + 16] = (unsigned short)bf16_rne(fmaxf(acc1[j] + bias1, 0.f));
            sX[row * 72 + colL + 32] = (unsigned short)bf16_rne(fmaxf(acc2[j] + bias2, 0.f));
            sX[row * 72 + colL + 48] = (unsigned short)bf16_rne(fmaxf(acc3[j] + bias3, 0.f));
        }
    }
    // wave w wrote rows 16w..16w+15 and reads only those: no barrier needed.
    f32x4 h0 = {0.f, 0.f, 0.f, 0.f}, h1 = h0;
#pragma unroll
    for (int s = 0; s < 2; ++s) {
        const int kb = s * 32 + kq * 8;
        bf16x8 a  = *(const bf16x8*)&sX[(16 * w + colL) * 72 + kb];
        bf16x8 b0 = *(const bf16x8*)&sBh[(colL +  0) * 72 + kb];
        bf16x8 b1 = *(const bf16x8*)&sBh[(colL + 16) * 72 + kb];
        h0 = __builtin_amdgcn_mfma_f32_16x16x32_bf16(a, b0, h0, 0, 0, 0);
        h1 = __builtin_amdgcn_mfma_f32_16x16x32_bf16(a, b1, h1, 0, 0, 0);
    }
    {
        const float bh1c0 = b_h1[colL];
        const float bh1c1 = b_h1[colL + 16];
        const float wh2c0 = W_h2[colL];
        const float wh2c1 = W_h2[colL + 16];
        const float bh2 = b_h2[0];
#pragma unroll
        for (int j = 0; j < 4; ++j) {
            float p = fmaxf(h0[j] + bh1c0, 0.f) * wh2c0 +
                      fmaxf(h1[j] + bh1c1, 0.f) * wh2c1;
            p += __shfl_xor(p, 1);
            p += __shfl_xor(p, 2);
            p += __shfl_xor(p, 4);
            p += __shfl_xor(p, 8);
            int grow = gbase + 16 * w + kq * 4 + j;
            if (colL == 0 && grow < n) out[grow] = p + bh2;
        }
    }
}

// ---------------------------------------------------------------------------
extern "C" void kernel_launch(void* const* d_in, const int* in_sizes, int n_in,
                              void* d_out, int out_size, void* d_ws, size_t ws_size,
                              hipStream_t stream) {
    const float* loc_feat = (const float*)d_in[0];
    const float* evt_feat = (const float*)d_in[1];
    const int*   qid      = (const int*)d_in[2];
    const int*   ei       = (const int*)d_in[3];
    const float* emb      = (const float*)d_in[4];
    const float* W_loc    = (const float*)d_in[5];
    const float* b_loc    = (const float*)d_in[6];
    const float* W_evt    = (const float*)d_in[7];
    const float* b_evt    = (const float*)d_in[8];
    const float* W_l      = (const float*)d_in[9];
    const float* b_l      = (const float*)d_in[10];
    const float* W_r      = (const float*)d_in[11];
    const float* W_h1     = (const float*)d_in[12];
    const float* b_h1     = (const float*)d_in[13];
    const float* W_h2     = (const float*)d_in[14];
    const float* b_h2     = (const float*)d_in[15];
    float* out = (float*)d_out;

    char* ws = (char*)d_ws;
    size_t off = 0;
    auto alloc = [&](size_t bytes) -> void* {
        void* p = ws + off;
        off += (bytes + 255) & ~(size_t)255;
        return p;
    };
    unsigned* evtb  = (unsigned*)alloc((size_t)(N_EVT + 1) * 32 * 4); // bf16 evt_x + zero row
    unsigned* locxb = (unsigned*)alloc((size_t)N_LOC * 32 * 4);       // 12.8 MB
    unsigned* meanb = (unsigned*)alloc((size_t)N_LOC * 32 * 4);       // 12.8 MB
    unsigned* seg   = (unsigned*)alloc((size_t)NBIN * NB * SEGCAP * 4); // 29.4 MB
    int*   cntm     = (int*)alloc((size_t)NBIN * NB * 4);             // 0.6 MB
    int*   deg      = (int*)alloc((size_t)N_LOC * 4);
    int*   row_ex   = (int*)alloc((size_t)(N_LOC + 1) * 4);
    int*   csr      = (int*)alloc((size_t)NB * BCAPP * 4);            // 14.4 MB
    (void)ws_size; (void)in_sizes; (void)n_in; (void)out_size;

    // L1: fused bin + evt + loc (391 + 1563 + 1563 blocks)
    k_front<<<NBIN + 2 * DGRID, 256, 0, stream>>>(
        evt_feat, W_evt, b_evt, (unsigned short*)evtb,
        loc_feat, qid, emb, W_loc, b_loc, (unsigned short*)locxb,
        ei, cntm, seg, evtb + (size_t)N_EVT * 32);
    k_bfill<<<NB, 256, 0, stream>>>(cntm, seg, deg, row_ex, csr);
    k_aggr<<<N_LOC / 4, 256, 0, stream>>>(evtb, row_ex, deg, csr, meanb, N_LOC);
    k_comb<<<DGRID, 256, 0, stream>>>(meanb, locxb, W_l, b_l, W_r,
                                      W_h1, b_h1, W_h2, b_h2, out, N_LOC);
}